// Round 1
// baseline (323.698 us; speedup 1.0000x reference)
//
#include <hip/hip_runtime.h>
#include <hip/hip_bf16.h>

// Implicit-GEMM conv: M = 32*54*54 = 93312, N = 256 (co), K = 9*256 = 2304.
// bf16 MFMA (16x16x32), 128x128 tile, BK=32, global_load_lds staging (m97 structure).

typedef __bf16 bf16x8 __attribute__((ext_vector_type(8)));
typedef float f32x4 __attribute__((ext_vector_type(4)));

#define GLOBAL_AS __attribute__((address_space(1)))
#define LDS_AS __attribute__((address_space(3)))

static __device__ __forceinline__ void glds16(const void* g, void* l) {
    __builtin_amdgcn_global_load_lds((const GLOBAL_AS unsigned int*)g,
                                     (LDS_AS unsigned int*)l, 16, 0, 0);
}

static __device__ __forceinline__ unsigned short f2bf(float f) {
    unsigned int u = __float_as_uint(f);
    unsigned int r = u + 0x7FFFu + ((u >> 16) & 1u);  // RNE
    return (unsigned short)(r >> 16);
}

// ---- x: fp32 (32,56,56,256) -> bf16 bits, 8 elems/thread ----
__global__ void cvt_x(const float* __restrict__ in, unsigned short* __restrict__ out, int n) {
    int i = (blockIdx.x * 256 + threadIdx.x) * 8;
    if (i >= n) return;
    const float4* p = (const float4*)(in + i);
    float4 a = p[0], b = p[1];
    uint4 v;
    v.x = (unsigned)f2bf(a.x) | ((unsigned)f2bf(a.y) << 16);
    v.y = (unsigned)f2bf(a.z) | ((unsigned)f2bf(a.w) << 16);
    v.z = (unsigned)f2bf(b.x) | ((unsigned)f2bf(b.y) << 16);
    v.w = (unsigned)f2bf(b.z) | ((unsigned)f2bf(b.w) << 16);
    *(uint4*)(out + i) = v;
}

// ---- w: OIHW fp32 (256,256,3,3), threshold, -> W_t[co][k], k = khw*256+ci ----
__global__ void cvt_w(const float* __restrict__ w, unsigned short* __restrict__ wt) {
    int co = blockIdx.x;
    int ci = threadIdx.x;
    const float* src = w + co * 2304 + ci * 9;
    unsigned short* dst = wt + co * 2304 + ci;
#pragma unroll
    for (int khw = 0; khw < 9; ++khw) {
        float v = src[khw];
        v = (fabsf(v) < 0.01f) ? 0.0f : v;
        dst[khw * 256] = f2bf(v);
    }
}

// ---- GEMM: Out[m][co] = sum_k A[m][k]*Wt[co][k] + bias[co] ----
// A[m][k]: m=(n,oh,ow), k=(kh,kw,ci): x[n][oh+kh][ow+kw][ci]
__global__ __launch_bounds__(256) void conv_gemm(
    const unsigned short* __restrict__ Xb,   // bf16 bits [32*56*56*256]
    const unsigned short* __restrict__ Wt,   // bf16 bits [256][2304]
    const float* __restrict__ bias,          // [256]
    float* __restrict__ Out)                 // [93312][256]
{
    __shared__ __align__(16) unsigned short As[128 * 32];  // [m][k] 8 KB
    __shared__ __align__(16) unsigned short Bs[128 * 32];  // [co][k] 8 KB

    const int tid  = threadIdx.x;
    const int lane = tid & 63;
    const int wave = tid >> 6;
    const int bx   = blockIdx.x;
    const int m0   = (bx >> 1) * 128;
    const int co0  = (bx & 1) * 128;

    // staging roles: tile[row][k], row = r*64 + wave*16 + (lane>>2), k-col = (lane&3)*8
    const int srow = lane >> 2;
    const int scol = (lane & 3) * 8;

    const unsigned short* a_src[2];
    const unsigned short* b_src[2];
#pragma unroll
    for (int r = 0; r < 2; ++r) {
        int row = r * 64 + wave * 16 + srow;
        int m = m0 + row;
        int n = m / 2916;
        int rem = m - n * 2916;
        int oh = rem / 54;
        int ow = rem - oh * 54;
        a_src[r] = Xb + (((n * 56 + oh) * 56 + ow) << 8) + scol;  // kh=kw=0, ci=scol
        b_src[r] = Wt + (co0 + row) * 2304 + scol;
    }
    // wave-uniform LDS dests (lane*16B contiguous per instruction)
    unsigned short* a_dst[2] = { As + wave * 512, As + 2048 + wave * 512 };
    unsigned short* b_dst[2] = { Bs + wave * 512, Bs + 2048 + wave * 512 };

    const int fm = lane & 15;  // A-row / B-col within 16
    const int fq = lane >> 4;  // k-quad
    const int wm = (wave >> 1) * 64;
    const int wn = (wave & 1) * 64;

    f32x4 acc[4][4];
#pragma unroll
    for (int i = 0; i < 4; ++i)
#pragma unroll
        for (int j = 0; j < 4; ++j)
            acc[i][j] = (f32x4){0.f, 0.f, 0.f, 0.f};

    int kc = 0;
    for (int khw = 0; khw < 9; ++khw) {
        const int kh = khw / 3;
        const int kw = khw - kh * 3;
        const int aoff0 = (kh * 56 + kw) << 8;  // spatial advance, elements
#pragma unroll 1
        for (int c = 0; c < 8; ++c, ++kc) {
            const int aoff = aoff0 + c * 32;
            const int boff = kc * 32;
            __syncthreads();  // previous iter's LDS reads complete
#pragma unroll
            for (int r = 0; r < 2; ++r) {
                glds16(a_src[r] + aoff, a_dst[r]);
                glds16(b_src[r] + boff, b_dst[r]);
            }
            __syncthreads();  // staging complete (vmcnt(0) drain)

            bf16x8 af[4], bfr[4];
#pragma unroll
            for (int mi = 0; mi < 4; ++mi)
                af[mi] = *(const bf16x8*)&As[(wm + mi * 16 + fm) * 32 + fq * 8];
#pragma unroll
            for (int ni = 0; ni < 4; ++ni)
                bfr[ni] = *(const bf16x8*)&Bs[(wn + ni * 16 + fm) * 32 + fq * 8];
#pragma unroll
            for (int mi = 0; mi < 4; ++mi)
#pragma unroll
                for (int ni = 0; ni < 4; ++ni)
                    acc[mi][ni] = __builtin_amdgcn_mfma_f32_16x16x32_bf16(
                        af[mi], bfr[ni], acc[mi][ni], 0, 0, 0);
        }
    }

    // epilogue: D col = lane&15 (co), row = (lane>>4)*4 + reg (m); fuse bias
    float bv[4];
#pragma unroll
    for (int ni = 0; ni < 4; ++ni) bv[ni] = bias[co0 + wn + ni * 16 + fm];
#pragma unroll
    for (int mi = 0; mi < 4; ++mi) {
#pragma unroll
        for (int reg = 0; reg < 4; ++reg) {
            int m = m0 + wm + mi * 16 + fq * 4 + reg;
            float* orow = Out + m * 256 + co0 + wn + fm;
#pragma unroll
            for (int ni = 0; ni < 4; ++ni)
                orow[ni * 16] = acc[mi][ni][reg] + bv[ni];
        }
    }
}

extern "C" void kernel_launch(void* const* d_in, const int* in_sizes, int n_in,
                              void* d_out, int out_size, void* d_ws, size_t ws_size,
                              hipStream_t stream) {
    const float* x    = (const float*)d_in[0];  // (32,56,56,256) fp32
    const float* w    = (const float*)d_in[1];  // (256,256,3,3) fp32
    const float* bias = (const float*)d_in[2];  // (256,) fp32
    float* out = (float*)d_out;                 // (32,54,54,256) fp32

    const int NX = 32 * 56 * 56 * 256;  // 25,690,112
    unsigned short* xb = (unsigned short*)d_ws;           // 51.4 MB
    unsigned short* wt = xb + NX;                          // +1.18 MB

    cvt_x<<<NX / (256 * 8), 256, 0, stream>>>(x, xb, NX);
    cvt_w<<<256, 256, 0, stream>>>(w, wt);
    conv_gemm<<<729 * 2, 256, 0, stream>>>(xb, wt, bias, out);
}

// Round 2
// 304.901 us; speedup vs baseline: 1.0617x; 1.0617x over previous
//
#include <hip/hip_runtime.h>
#include <hip/hip_bf16.h>

// Implicit-GEMM conv: M = 32*54*54 = 93312, N = 256 (co), K = 9*256 = 2304.
// bf16 MFMA (16x16x32), 128x128 tile, BK=32, global_load_lds staging.
// R2: XOR-swizzled LDS k-slots (kill 8-way bank conflicts -> 2-way free),
//     XCD-contiguous block remap (cross-block x-row reuse in per-XCD L2).

typedef __bf16 bf16x8 __attribute__((ext_vector_type(8)));
typedef float f32x4 __attribute__((ext_vector_type(4)));

#define GLOBAL_AS __attribute__((address_space(1)))
#define LDS_AS __attribute__((address_space(3)))

static __device__ __forceinline__ void glds16(const void* g, void* l) {
    __builtin_amdgcn_global_load_lds((const GLOBAL_AS unsigned int*)g,
                                     (LDS_AS unsigned int*)l, 16, 0, 0);
}

static __device__ __forceinline__ unsigned short f2bf(float f) {
    unsigned int u = __float_as_uint(f);
    unsigned int r = u + 0x7FFFu + ((u >> 16) & 1u);  // RNE
    return (unsigned short)(r >> 16);
}

// ---- x: fp32 (32,56,56,256) -> bf16 bits, 8 elems/thread ----
__global__ void cvt_x(const float* __restrict__ in, unsigned short* __restrict__ out, int n) {
    int i = (blockIdx.x * 256 + threadIdx.x) * 8;
    if (i >= n) return;
    const float4* p = (const float4*)(in + i);
    float4 a = p[0], b = p[1];
    uint4 v;
    v.x = (unsigned)f2bf(a.x) | ((unsigned)f2bf(a.y) << 16);
    v.y = (unsigned)f2bf(a.z) | ((unsigned)f2bf(a.w) << 16);
    v.z = (unsigned)f2bf(b.x) | ((unsigned)f2bf(b.y) << 16);
    v.w = (unsigned)f2bf(b.z) | ((unsigned)f2bf(b.w) << 16);
    *(uint4*)(out + i) = v;
}

// ---- w: OIHW fp32 (256,256,3,3), threshold, -> W_t[co][k], k = khw*256+ci ----
__global__ void cvt_w(const float* __restrict__ w, unsigned short* __restrict__ wt) {
    int co = blockIdx.x;
    int ci = threadIdx.x;
    const float* src = w + co * 2304 + ci * 9;
    unsigned short* dst = wt + co * 2304 + ci;
#pragma unroll
    for (int khw = 0; khw < 9; ++khw) {
        float v = src[khw];
        v = (fabsf(v) < 0.01f) ? 0.0f : v;
        dst[khw * 256] = f2bf(v);
    }
}

// LDS swizzle: row's global k-chunk g (8 bf16) lives at slot g ^ key(row),
// key(row) = (row&3) ^ ((row>>2)&3)  -- row identity mod 16 (tile rows are
// grouped in 16s, so all base offsets are multiples of 16).
static __device__ __forceinline__ int swz_key(int row16) {
    return (row16 & 3) ^ ((row16 >> 2) & 3);
}

// ---- GEMM: Out[m][co] = sum_k A[m][k]*Wt[co][k] + bias[co] ----
__global__ __launch_bounds__(256) void conv_gemm(
    const unsigned short* __restrict__ Xb,   // bf16 bits [32*56*56*256]
    const unsigned short* __restrict__ Wt,   // bf16 bits [256][2304]
    const float* __restrict__ bias,          // [256]
    float* __restrict__ Out)                 // [93312][256]
{
    __shared__ __align__(16) unsigned short As[128 * 32];  // [m][k-slots] 8 KB
    __shared__ __align__(16) unsigned short Bs[128 * 32];  // [co][k-slots] 8 KB

    const int tid  = threadIdx.x;
    const int lane = tid & 63;
    const int wave = tid >> 6;

    // XCD-contiguous remap: assume dispatch d -> XCD d%8. Give XCD x the
    // contiguous virtual range [x*182 + min(x,2), ...). 1458 = 8*182 + 2.
    const int bx = blockIdx.x;
    const int xcd = bx & 7;
    const int slt = bx >> 3;
    const int v   = xcd * 182 + (xcd < 2 ? xcd : 2) + slt;
    const int m0  = (v >> 1) * 128;
    const int co0 = (v & 1) * 128;

    // staging: lane covers tile row (r*64 + wave*16 + srow), k-chunk schunk_g
    const int srow = lane >> 2;
    const int schunk_g = (lane & 3) ^ swz_key(srow);  // swizzled global chunk
    const int scol = schunk_g * 8;

    const unsigned short* a_src[2];
    const unsigned short* b_src[2];
#pragma unroll
    for (int r = 0; r < 2; ++r) {
        int row = r * 64 + wave * 16 + srow;
        int m = m0 + row;
        int n = m / 2916;
        int rem = m - n * 2916;
        int oh = rem / 54;
        int ow = rem - oh * 54;
        a_src[r] = Xb + (((n * 56 + oh) * 56 + ow) << 8) + scol;  // kh=kw=0
        b_src[r] = Wt + (co0 + row) * 2304 + scol;
    }
    unsigned short* a_dst[2] = { As + wave * 512, As + 2048 + wave * 512 };
    unsigned short* b_dst[2] = { Bs + wave * 512, Bs + 2048 + wave * 512 };

    const int fm = lane & 15;  // A-row / B-col within 16
    const int fq = lane >> 4;  // k-quad (global chunk index to read)
    const int wm = (wave >> 1) * 64;
    const int wn = (wave & 1) * 64;
    const int slot8 = (fq ^ swz_key(fm)) * 8;  // swizzled LDS column (elems)

    f32x4 acc[4][4];
#pragma unroll
    for (int i = 0; i < 4; ++i)
#pragma unroll
        for (int j = 0; j < 4; ++j)
            acc[i][j] = (f32x4){0.f, 0.f, 0.f, 0.f};

    int kc = 0;
    for (int khw = 0; khw < 9; ++khw) {
        const int kh = khw / 3;
        const int kw = khw - kh * 3;
        const int aoff0 = (kh * 56 + kw) << 8;
#pragma unroll 1
        for (int c = 0; c < 8; ++c, ++kc) {
            const int aoff = aoff0 + c * 32;
            const int boff = kc * 32;
            __syncthreads();
#pragma unroll
            for (int r = 0; r < 2; ++r) {
                glds16(a_src[r] + aoff, a_dst[r]);
                glds16(b_src[r] + boff, b_dst[r]);
            }
            __syncthreads();

            bf16x8 af[4], bfr[4];
#pragma unroll
            for (int mi = 0; mi < 4; ++mi)
                af[mi] = *(const bf16x8*)&As[(wm + mi * 16 + fm) * 32 + slot8];
#pragma unroll
            for (int ni = 0; ni < 4; ++ni)
                bfr[ni] = *(const bf16x8*)&Bs[(wn + ni * 16 + fm) * 32 + slot8];
#pragma unroll
            for (int mi = 0; mi < 4; ++mi)
#pragma unroll
                for (int ni = 0; ni < 4; ++ni)
                    acc[mi][ni] = __builtin_amdgcn_mfma_f32_16x16x32_bf16(
                        af[mi], bfr[ni], acc[mi][ni], 0, 0, 0);
        }
    }

    // epilogue: D col = lane&15 (co), row = (lane>>4)*4 + reg (m); fuse bias
    float bv[4];
#pragma unroll
    for (int ni = 0; ni < 4; ++ni) bv[ni] = bias[co0 + wn + ni * 16 + fm];
#pragma unroll
    for (int mi = 0; mi < 4; ++mi) {
#pragma unroll
        for (int reg = 0; reg < 4; ++reg) {
            int m = m0 + wm + mi * 16 + fq * 4 + reg;
            float* orow = Out + m * 256 + co0 + wn + fm;
#pragma unroll
            for (int ni = 0; ni < 4; ++ni)
                orow[ni * 16] = acc[mi][ni][reg] + bv[ni];
        }
    }
}

extern "C" void kernel_launch(void* const* d_in, const int* in_sizes, int n_in,
                              void* d_out, int out_size, void* d_ws, size_t ws_size,
                              hipStream_t stream) {
    const float* x    = (const float*)d_in[0];  // (32,56,56,256) fp32
    const float* w    = (const float*)d_in[1];  // (256,256,3,3) fp32
    const float* bias = (const float*)d_in[2];  // (256,) fp32
    float* out = (float*)d_out;                 // (32,54,54,256) fp32

    const int NX = 32 * 56 * 56 * 256;  // 25,690,112
    unsigned short* xb = (unsigned short*)d_ws;
    unsigned short* wt = xb + NX;

    cvt_x<<<NX / (256 * 8), 256, 0, stream>>>(x, xb, NX);
    cvt_w<<<256, 256, 0, stream>>>(w, wt);
    conv_gemm<<<729 * 2, 256, 0, stream>>>(xb, wt, bias, out);
}

// Round 3
// 302.543 us; speedup vs baseline: 1.0699x; 1.0078x over previous
//
#include <hip/hip_runtime.h>
#include <hip/hip_bf16.h>

// Implicit-GEMM conv: M = 32*54*54 = 93312, N = 256 (co), K = 9*256 = 2304.
// bf16 MFMA (16x16x32), 128x128 tile, BK=32, global_load_lds staging.
// R3: single-barrier double-buffered K-loop (glds prefetch of chunk c+1 issued
//     after the barrier, compute on the other buffer -> vmcnt(0) drain is for
//     loads issued a full iteration earlier). cvt_x+cvt_w merged into one launch.

typedef __bf16 bf16x8 __attribute__((ext_vector_type(8)));
typedef float f32x4 __attribute__((ext_vector_type(4)));

#define GLOBAL_AS __attribute__((address_space(1)))
#define LDS_AS __attribute__((address_space(3)))

static __device__ __forceinline__ void glds16(const void* g, void* l) {
    __builtin_amdgcn_global_load_lds((const GLOBAL_AS unsigned int*)g,
                                     (LDS_AS unsigned int*)l, 16, 0, 0);
}

static __device__ __forceinline__ unsigned short f2bf(float f) {
    unsigned int u = __float_as_uint(f);
    unsigned int r = u + 0x7FFFu + ((u >> 16) & 1u);  // RNE
    return (unsigned short)(r >> 16);
}

// ---- combined conversion: blocks [0,12544) convert x, [12544,12800) convert w ----
__global__ void cvt_xw(const float* __restrict__ x, unsigned short* __restrict__ xb,
                       const float* __restrict__ w, unsigned short* __restrict__ wt) {
    const int NXB = 32 * 56 * 56 * 256 / (256 * 8);  // 12544
    if (blockIdx.x < NXB) {
        int i = (blockIdx.x * 256 + threadIdx.x) * 8;
        const float4* p = (const float4*)(x + i);
        float4 a = p[0], b = p[1];
        uint4 v;
        v.x = (unsigned)f2bf(a.x) | ((unsigned)f2bf(a.y) << 16);
        v.y = (unsigned)f2bf(a.z) | ((unsigned)f2bf(a.w) << 16);
        v.z = (unsigned)f2bf(b.x) | ((unsigned)f2bf(b.y) << 16);
        v.w = (unsigned)f2bf(b.z) | ((unsigned)f2bf(b.w) << 16);
        *(uint4*)(xb + i) = v;
    } else {
        int co = blockIdx.x - NXB;
        int ci = threadIdx.x;
        const float* src = w + co * 2304 + ci * 9;
        unsigned short* dst = wt + co * 2304 + ci;
#pragma unroll
        for (int khw = 0; khw < 9; ++khw) {
            float v = src[khw];
            v = (fabsf(v) < 0.01f) ? 0.0f : v;
            dst[khw * 256] = f2bf(v);
        }
    }
}

// LDS swizzle: row's global k-chunk g (8 bf16) lives at slot g ^ key(row mod 16).
static __device__ __forceinline__ int swz_key(int row16) {
    return (row16 & 3) ^ ((row16 >> 2) & 3);
}

// ---- GEMM: Out[m][co] = sum_k A[m][k]*Wt[co][k] + bias[co] ----
__global__ __launch_bounds__(256) void conv_gemm(
    const unsigned short* __restrict__ Xb,   // bf16 bits [32*56*56*256]
    const unsigned short* __restrict__ Wt,   // bf16 bits [256][2304]
    const float* __restrict__ bias,          // [256]
    float* __restrict__ Out)                 // [93312][256]
{
    // double-buffered: [buf][row][k-slots], 8 KB per tile-buffer, 32 KB total
    __shared__ __align__(16) unsigned short As[2][128 * 32];
    __shared__ __align__(16) unsigned short Bs[2][128 * 32];

    const int tid  = threadIdx.x;
    const int lane = tid & 63;
    const int wave = tid >> 6;

    // XCD-contiguous remap (d -> XCD d%8): XCD x owns a contiguous virtual range.
    const int bx = blockIdx.x;
    const int xcd = bx & 7;
    const int slt = bx >> 3;
    const int v   = xcd * 182 + (xcd < 2 ? xcd : 2) + slt;  // 1458 = 8*182+2
    const int m0  = (v >> 1) * 128;
    const int co0 = (v & 1) * 128;

    // staging: lane covers tile row (r*64 + wave*16 + srow), swizzled k-chunk
    const int srow = lane >> 2;
    const int schunk_g = (lane & 3) ^ swz_key(srow);
    const int scol = schunk_g * 8;

    const unsigned short* a_src[2];
    const unsigned short* b_src[2];
#pragma unroll
    for (int r = 0; r < 2; ++r) {
        int row = r * 64 + wave * 16 + srow;
        int m = m0 + row;
        int n = m / 2916;
        int rem = m - n * 2916;
        int oh = rem / 54;
        int ow = rem - oh * 54;
        a_src[r] = Xb + (((n * 56 + oh) * 56 + ow) << 8) + scol;  // kh=kw=0
        b_src[r] = Wt + (co0 + row) * 2304 + scol;
    }

    const int fm = lane & 15;  // A-row / B-col within 16
    const int fq = lane >> 4;  // global k-chunk index to read
    const int wm = (wave >> 1) * 64;
    const int wn = (wave & 1) * 64;
    const int slot8 = (fq ^ swz_key(fm)) * 8;  // swizzled LDS column (elems)

    f32x4 acc[4][4];
#pragma unroll
    for (int i = 0; i < 4; ++i)
#pragma unroll
        for (int j = 0; j < 4; ++j)
            acc[i][j] = (f32x4){0.f, 0.f, 0.f, 0.f};

    // prologue: stage chunk 0 into buffer 0
#pragma unroll
    for (int r = 0; r < 2; ++r) {
        glds16(a_src[r], &As[0][wave * 512 + r * 2048]);
        glds16(b_src[r], &Bs[0][wave * 512 + r * 2048]);
    }

#pragma unroll 1
    for (int kc = 0; kc < 72; ++kc) {
        // barrier: (a) vmcnt(0) -> stage(kc) [issued last iter] complete;
        //          (b) all waves done reading buf[(kc+1)&1] (iter kc-1 reads)
        __syncthreads();

        if (kc < 71) {
            const int kcn = kc + 1;
            const int khwn = kcn >> 3;
            const int khn = (khwn * 11) >> 5;       // khwn/3 for 0..8
            const int kwn = khwn - khn * 3;
            const int aoffn = ((khn * 56 + kwn) << 8) + (kcn & 7) * 32;
            const int boffn = kcn * 32;
            const int b = kcn & 1;
#pragma unroll
            for (int r = 0; r < 2; ++r) {
                glds16(a_src[r] + aoffn, &As[b][wave * 512 + r * 2048]);
                glds16(b_src[r] + boffn, &Bs[b][wave * 512 + r * 2048]);
            }
        }

        const unsigned short* Ab = As[kc & 1];
        const unsigned short* Bb = Bs[kc & 1];
        bf16x8 af[4], bfr[4];
#pragma unroll
        for (int mi = 0; mi < 4; ++mi)
            af[mi] = *(const bf16x8*)&Ab[(wm + mi * 16 + fm) * 32 + slot8];
#pragma unroll
        for (int ni = 0; ni < 4; ++ni)
            bfr[ni] = *(const bf16x8*)&Bb[(wn + ni * 16 + fm) * 32 + slot8];
#pragma unroll
        for (int mi = 0; mi < 4; ++mi)
#pragma unroll
            for (int ni = 0; ni < 4; ++ni)
                acc[mi][ni] = __builtin_amdgcn_mfma_f32_16x16x32_bf16(
                    af[mi], bfr[ni], acc[mi][ni], 0, 0, 0);
    }

    // epilogue: D col = lane&15 (co), row = (lane>>4)*4 + reg (m); fuse bias
    float bv[4];
#pragma unroll
    for (int ni = 0; ni < 4; ++ni) bv[ni] = bias[co0 + wn + ni * 16 + fm];
#pragma unroll
    for (int mi = 0; mi < 4; ++mi) {
#pragma unroll
        for (int reg = 0; reg < 4; ++reg) {
            int m = m0 + wm + mi * 16 + fq * 4 + reg;
            float* orow = Out + m * 256 + co0 + wn + fm;
#pragma unroll
            for (int ni = 0; ni < 4; ++ni)
                orow[ni * 16] = acc[mi][ni][reg] + bv[ni];
        }
    }
}

extern "C" void kernel_launch(void* const* d_in, const int* in_sizes, int n_in,
                              void* d_out, int out_size, void* d_ws, size_t ws_size,
                              hipStream_t stream) {
    const float* x    = (const float*)d_in[0];  // (32,56,56,256) fp32
    const float* w    = (const float*)d_in[1];  // (256,256,3,3) fp32
    const float* bias = (const float*)d_in[2];  // (256,) fp32
    float* out = (float*)d_out;                 // (32,54,54,256) fp32

    const int NX = 32 * 56 * 56 * 256;  // 25,690,112
    unsigned short* xb = (unsigned short*)d_ws;
    unsigned short* wt = xb + NX;

    cvt_xw<<<NX / (256 * 8) + 256, 256, 0, stream>>>(x, xb, w, wt);
    conv_gemm<<<729 * 2, 256, 0, stream>>>(xb, wt, bias, out);
}